// Round 8
// baseline (441.487 us; speedup 1.0000x reference)
//
#include <hip/hip_runtime.h>
#include <hip/hip_cooperative_groups.h>

namespace cg = cooperative_groups;

// DropBlock, N=64 C=64 H=80 W=80, block_size=5 (top/left-clipped window max).
// R8: single cooperative kernel. Phase A: bitboard window-OR (ballot pack ->
// 128-bit row sliding-OR -> 5-row col OR) into LDS, per-plane zero counts to
// global. grid.sync(). Every block sums the 4096 counts (16KB, L3) -> scale.
// Phase B: float4 stream apply from LDS masks. No bits round-trip, no second
// dispatch. Fallback: R7 two-kernel path if cooperative launch unavailable.
#define DB_H 80
#define DB_W 80
#define DB_PLANE (DB_H * DB_W)               // 6400
#define DB_NPLANES 4096                      // N*C
#define DB_ROW_WORDS 3
#define DB_PLANE_WORDS (DB_H * DB_ROW_WORDS) // 240
#define DB_TOTAL (DB_PLANE * DB_NPLANES)     // 26214400
#define DB_COUNT_F 26214400.0f               // 25 * 2^20 — exact in f32
#define DB_CNT_BYTES (DB_NPLANES * 4)        // 16384
#define DB_NBLK 2048                         // fused: 2 planes/block, 8/CU
#define PPBLK 2
#define WPB 4                                // recompute fallback only

// ---------------- Fused cooperative kernel ----------------
__global__ __launch_bounds__(256, 8) void db_fused(
    const int* __restrict__ mask,
    const float4* __restrict__ x4,
    unsigned int* __restrict__ counts,
    float4* __restrict__ out4)
{
    __shared__ unsigned long long P[PPBLK][104];        // packed seed bits
    __shared__ unsigned int RO[PPBLK][DB_PLANE_WORDS];  // row-OR
    __shared__ unsigned int BM[PPBLK][DB_PLANE_WORDS];  // block mask
    __shared__ unsigned int ZP[PPBLK][2];
    __shared__ float s_scale;
    __shared__ unsigned int s_part[4];
    const int t = threadIdx.x;
    const int wid = t >> 6, lane = t & 63;
    const int pib = wid >> 1, half = wid & 1;
    const int plane = blockIdx.x * PPBLK + pib;
    const int* mp = mask + plane * DB_PLANE;
    unsigned long long* Pp = P[pib];
    unsigned int* ro = RO[pib];

    // Phase A1: this wave packs qwords [half*50, half*50+50) in bursts of 10.
    #pragma unroll 1
    for (int c = 0; c < 5; ++c) {
        int v[10];
        const int base = half * 50 + c * 10;
        #pragma unroll
        for (int k = 0; k < 10; ++k) v[k] = mp[(base + k) * 64 + lane];
        #pragma unroll
        for (int k = 0; k < 10; ++k) {
            unsigned long long bal = __ballot(v[k] & 1);
            if (lane == 0) Pp[base + k] = bal;
        }
    }
    if (t < 2 * 4) P[t >> 2][100 + (t & 3)] = 0ULL;
    __syncthreads();

    // Phase A2: row sliding-OR (width 5, left-clipped) for 40 rows per wave.
    if (lane < 40) {
        const int r = half * 40 + lane;
        const int bitpos = r * DB_W;
        const int q = bitpos >> 6, off = bitpos & 63;
        unsigned long long a, b;
        if (off) {
            a = (Pp[q] >> off) | (Pp[q + 1] << (64 - off));
            b = (Pp[q + 1] >> off) | (Pp[q + 2] << (64 - off));
        } else {
            a = Pp[q]; b = Pp[q + 1];
        }
        b &= 0xFFFFULL;
        unsigned long long ra = a, rb = b;
        #pragma unroll
        for (int s = 1; s <= 4; ++s) {
            ra |= a << s;
            rb |= (b << s) | (a >> (64 - s));
        }
        rb &= 0xFFFFULL;
        ro[r * 3 + 0] = (unsigned int)ra;
        ro[r * 3 + 1] = (unsigned int)(ra >> 32);
        ro[r * 3 + 2] = (unsigned int)rb;
    }
    __syncthreads();

    // Phase A3: col OR over rows i-4..i, zeros count, mask -> LDS BM.
    unsigned int zeros = 0;
    if (lane < 40) {
        const int i = half * 40 + lane;
        const int lo = (i >= 4) ? i - 4 : 0;
        unsigned int c0 = 0, c1 = 0, c2 = 0;
        for (int ii = lo; ii <= i; ++ii) {
            c0 |= ro[ii * 3 + 0];
            c1 |= ro[ii * 3 + 1];
            c2 |= ro[ii * 3 + 2];
        }
        zeros = 80u - __popc(c0) - __popc(c1) - __popc(c2);
        BM[pib][i * 3 + 0] = c0;
        BM[pib][i * 3 + 1] = c1;
        BM[pib][i * 3 + 2] = c2;
    }
    for (int off = 32; off > 0; off >>= 1)
        zeros += (unsigned int)__shfl_down((int)zeros, off, 64);
    if (lane == 0) ZP[pib][half] = zeros;
    __syncthreads();
    if (t < PPBLK)
        counts[blockIdx.x * PPBLK + t] = ZP[t][0] + ZP[t][1];
    __threadfence();

    cg::this_grid().sync();

    // Scale: every block sums the 4096 counts (16 KB, L3-resident).
    {
        const uint4* cp = (const uint4*)counts;   // 1024 uint4
        unsigned int c = 0;
        #pragma unroll
        for (int k = 0; k < 4; ++k) {
            uint4 v = cp[k * 256 + t];
            c += v.x + v.y + v.z + v.w;
        }
        for (int off = 32; off > 0; off >>= 1)
            c += (unsigned int)__shfl_down((int)c, off, 64);
        if ((t & 63) == 0) s_part[t >> 6] = c;
        __syncthreads();
        if (t == 0)
            s_scale = DB_COUNT_F /
                      (float)(s_part[0] + s_part[1] + s_part[2] + s_part[3]);
        __syncthreads();
    }
    const float scale = s_scale;

    // Phase B: apply both planes from LDS masks (coalesced float4 stream).
    #pragma unroll 1
    for (int p = 0; p < PPBLK; ++p) {
        const int pl = blockIdx.x * PPBLK + p;
        const float4* xp = x4 + pl * (DB_PLANE / 4);
        float4* op = out4 + pl * (DB_PLANE / 4);
        const unsigned int* bm = BM[p];
        #pragma unroll 1
        for (int g = t; g < DB_PLANE / 4; g += 256) {
            const int ep = g * 4;
            const int i = ep / DB_W;
            const int j = ep - i * DB_W;          // j%4==0, within one word
            const unsigned int nib = (bm[i * 3 + (j >> 5)] >> (j & 31)) & 0xFu;
            float4 v = make_float4(0.f, 0.f, 0.f, 0.f);
            if (nib != 0xFu) v = xp[g];
            float4 o;
            o.x = (nib & 1u) ? 0.0f : v.x * scale;
            o.y = (nib & 2u) ? 0.0f : v.y * scale;
            o.z = (nib & 4u) ? 0.0f : v.z * scale;
            o.w = (nib & 8u) ? 0.0f : v.w * scale;
            op[g] = o;
        }
    }
}

// ---------------- Fallback path A: R7 two-kernel (bits in ws) -------------
__global__ __launch_bounds__(256) void db_mask_kernel(
    const int* __restrict__ mask,
    unsigned int* __restrict__ bits,
    unsigned int* __restrict__ counts)
{
    __shared__ unsigned long long P[PPBLK][104];
    __shared__ unsigned int RO[PPBLK][DB_PLANE_WORDS];
    __shared__ unsigned int ZP[PPBLK][2];
    const int t = threadIdx.x;
    const int wid = t >> 6, lane = t & 63;
    const int pib = wid >> 1, half = wid & 1;
    const int plane = blockIdx.x * PPBLK + pib;
    const int* mp = mask + plane * DB_PLANE;
    unsigned long long* Pp = P[pib];
    unsigned int* ro = RO[pib];

    #pragma unroll 1
    for (int c = 0; c < 5; ++c) {
        int v[10];
        const int base = half * 50 + c * 10;
        #pragma unroll
        for (int k = 0; k < 10; ++k) v[k] = mp[(base + k) * 64 + lane];
        #pragma unroll
        for (int k = 0; k < 10; ++k) {
            unsigned long long bal = __ballot(v[k] & 1);
            if (lane == 0) Pp[base + k] = bal;
        }
    }
    if (t < 2 * 4) P[t >> 2][100 + (t & 3)] = 0ULL;
    __syncthreads();

    if (lane < 40) {
        const int r = half * 40 + lane;
        const int bitpos = r * DB_W;
        const int q = bitpos >> 6, off = bitpos & 63;
        unsigned long long a, b;
        if (off) {
            a = (Pp[q] >> off) | (Pp[q + 1] << (64 - off));
            b = (Pp[q + 1] >> off) | (Pp[q + 2] << (64 - off));
        } else {
            a = Pp[q]; b = Pp[q + 1];
        }
        b &= 0xFFFFULL;
        unsigned long long ra = a, rb = b;
        #pragma unroll
        for (int s = 1; s <= 4; ++s) {
            ra |= a << s;
            rb |= (b << s) | (a >> (64 - s));
        }
        rb &= 0xFFFFULL;
        ro[r * 3 + 0] = (unsigned int)ra;
        ro[r * 3 + 1] = (unsigned int)(ra >> 32);
        ro[r * 3 + 2] = (unsigned int)rb;
    }
    __syncthreads();

    unsigned int zeros = 0;
    if (lane < 40) {
        const int i = half * 40 + lane;
        const int lo = (i >= 4) ? i - 4 : 0;
        unsigned int c0 = 0, c1 = 0, c2 = 0;
        for (int ii = lo; ii <= i; ++ii) {
            c0 |= ro[ii * 3 + 0];
            c1 |= ro[ii * 3 + 1];
            c2 |= ro[ii * 3 + 2];
        }
        zeros = 80u - __popc(c0) - __popc(c1) - __popc(c2);
        unsigned int* bp = bits + plane * DB_PLANE_WORDS + i * 3;
        bp[0] = c0; bp[1] = c1; bp[2] = c2;
    }
    for (int off = 32; off > 0; off >>= 1)
        zeros += (unsigned int)__shfl_down((int)zeros, off, 64);
    if (lane == 0) ZP[pib][half] = zeros;
    __syncthreads();
    if (lane == 0 && half == 0)
        counts[plane] = ZP[pib][0] + ZP[pib][1];
}

__global__ __launch_bounds__(256) void db_apply_bits(
    const float4* __restrict__ x,
    const unsigned int* __restrict__ bits,
    const unsigned int* __restrict__ counts,
    float4* __restrict__ out)
{
    __shared__ float s_scale;
    __shared__ unsigned int s_part[4];
    {
        const uint4* cp = (const uint4*)counts;
        unsigned int c = 0;
        #pragma unroll
        for (int k = 0; k < 4; ++k) {
            uint4 v = cp[k * 256 + threadIdx.x];
            c += v.x + v.y + v.z + v.w;
        }
        for (int off = 32; off > 0; off >>= 1)
            c += (unsigned int)__shfl_down((int)c, off, 64);
        if ((threadIdx.x & 63) == 0) s_part[threadIdx.x >> 6] = c;
        __syncthreads();
        if (threadIdx.x == 0)
            s_scale = DB_COUNT_F /
                      (float)(s_part[0] + s_part[1] + s_part[2] + s_part[3]);
        __syncthreads();
    }
    const float scale = s_scale;
    const int NG = DB_TOTAL / 4;
    const int stride = gridDim.x * blockDim.x;
    #pragma unroll 2
    for (int g = blockIdx.x * blockDim.x + threadIdx.x; g < NG; g += stride) {
        int e = g * 4;
        int plane = e / DB_PLANE;
        int ep = e - plane * DB_PLANE;
        int i = ep / DB_W;
        int j = ep - i * DB_W;
        unsigned int nib =
            (bits[plane * DB_PLANE_WORDS + i * 3 + (j >> 5)] >> (j & 31)) & 0xFu;
        float4 v = make_float4(0.f, 0.f, 0.f, 0.f);
        if (nib != 0xFu) v = x[g];
        float4 o;
        o.x = (nib & 1u) ? 0.0f : v.x * scale;
        o.y = (nib & 2u) ? 0.0f : v.y * scale;
        o.z = (nib & 4u) ? 0.0f : v.z * scale;
        o.w = (nib & 8u) ? 0.0f : v.w * scale;
        out[g] = o;
    }
}

// ---------------- Fallback path B: recompute (tiny ws) --------------------
__global__ __launch_bounds__(256) void db_count_kernel(
    const int* __restrict__ mask,
    unsigned int* __restrict__ counts)
{
    __shared__ unsigned long long P[WPB][104];
    __shared__ unsigned int RO[WPB][DB_PLANE_WORDS];
    const int wid = threadIdx.x >> 6, lane = threadIdx.x & 63;
    const int plane = blockIdx.x * WPB + wid;
    const int* mp = mask + plane * DB_PLANE;
    unsigned long long* Pp = P[wid];
    unsigned int* ro = RO[wid];
    #pragma unroll 1
    for (int c = 0; c < 10; ++c) {
        int v[10];
        #pragma unroll
        for (int k = 0; k < 10; ++k) v[k] = mp[(c * 10 + k) * 64 + lane];
        #pragma unroll
        for (int k = 0; k < 10; ++k) {
            unsigned long long bal = __ballot(v[k] & 1);
            if (lane == 0) Pp[c * 10 + k] = bal;
        }
    }
    if (lane < 4) Pp[100 + lane] = 0ULL;
    __syncthreads();
    for (int r = lane; r < DB_H; r += 64) {
        const int bitpos = r * DB_W;
        const int q = bitpos >> 6, off = bitpos & 63;
        unsigned long long a, b;
        if (off) {
            a = (Pp[q] >> off) | (Pp[q + 1] << (64 - off));
            b = (Pp[q + 1] >> off) | (Pp[q + 2] << (64 - off));
        } else {
            a = Pp[q]; b = Pp[q + 1];
        }
        b &= 0xFFFFULL;
        unsigned long long ra = a, rb = b;
        #pragma unroll
        for (int s = 1; s <= 4; ++s) {
            ra |= a << s;
            rb |= (b << s) | (a >> (64 - s));
        }
        rb &= 0xFFFFULL;
        ro[r * 3 + 0] = (unsigned int)ra;
        ro[r * 3 + 1] = (unsigned int)(ra >> 32);
        ro[r * 3 + 2] = (unsigned int)rb;
    }
    __syncthreads();
    unsigned int zeros = 0;
    for (int i = lane; i < DB_H; i += 64) {
        const int lo = (i >= 4) ? i - 4 : 0;
        unsigned int c0 = 0, c1 = 0, c2 = 0;
        for (int ii = lo; ii <= i; ++ii) {
            c0 |= ro[ii * 3 + 0];
            c1 |= ro[ii * 3 + 1];
            c2 |= ro[ii * 3 + 2];
        }
        zeros += 80u - __popc(c0) - __popc(c1) - __popc(c2);
    }
    for (int off = 32; off > 0; off >>= 1)
        zeros += (unsigned int)__shfl_down((int)zeros, off, 64);
    if (lane == 0) counts[plane] = zeros;
}

__global__ __launch_bounds__(256) void db_apply_recompute(
    const float* __restrict__ x,
    const int* __restrict__ mask,
    const unsigned int* __restrict__ counts,
    float* __restrict__ out)
{
    __shared__ unsigned long long P[WPB][104];
    __shared__ unsigned int RO[WPB][DB_PLANE_WORDS];
    __shared__ unsigned int BM[WPB][DB_PLANE_WORDS];
    __shared__ float s_scale;
    __shared__ unsigned int s_part[4];
    {
        const uint4* cp = (const uint4*)counts;
        unsigned int c = 0;
        #pragma unroll
        for (int k = 0; k < 4; ++k) {
            uint4 v = cp[k * 256 + threadIdx.x];
            c += v.x + v.y + v.z + v.w;
        }
        for (int off = 32; off > 0; off >>= 1)
            c += (unsigned int)__shfl_down((int)c, off, 64);
        if ((threadIdx.x & 63) == 0) s_part[threadIdx.x >> 6] = c;
        __syncthreads();
        if (threadIdx.x == 0)
            s_scale = DB_COUNT_F /
                      (float)(s_part[0] + s_part[1] + s_part[2] + s_part[3]);
        __syncthreads();
    }
    const float scale = s_scale;
    const int wid = threadIdx.x >> 6, lane = threadIdx.x & 63;
    const int plane = blockIdx.x * WPB + wid;
    const int* mp = mask + plane * DB_PLANE;
    unsigned long long* Pp = P[wid];
    unsigned int* ro = RO[wid];
    #pragma unroll 1
    for (int c = 0; c < 10; ++c) {
        int v[10];
        #pragma unroll
        for (int k = 0; k < 10; ++k) v[k] = mp[(c * 10 + k) * 64 + lane];
        #pragma unroll
        for (int k = 0; k < 10; ++k) {
            unsigned long long bal = __ballot(v[k] & 1);
            if (lane == 0) Pp[c * 10 + k] = bal;
        }
    }
    if (lane < 4) Pp[100 + lane] = 0ULL;
    __syncthreads();
    for (int r = lane; r < DB_H; r += 64) {
        const int bitpos = r * DB_W;
        const int q = bitpos >> 6, off = bitpos & 63;
        unsigned long long a, b;
        if (off) {
            a = (Pp[q] >> off) | (Pp[q + 1] << (64 - off));
            b = (Pp[q + 1] >> off) | (Pp[q + 2] << (64 - off));
        } else {
            a = Pp[q]; b = Pp[q + 1];
        }
        b &= 0xFFFFULL;
        unsigned long long ra = a, rb = b;
        #pragma unroll
        for (int s = 1; s <= 4; ++s) {
            ra |= a << s;
            rb |= (b << s) | (a >> (64 - s));
        }
        rb &= 0xFFFFULL;
        ro[r * 3 + 0] = (unsigned int)ra;
        ro[r * 3 + 1] = (unsigned int)(ra >> 32);
        ro[r * 3 + 2] = (unsigned int)rb;
    }
    __syncthreads();
    unsigned int* bmp = BM[wid];
    for (int i = lane; i < DB_H; i += 64) {
        const int lo = (i >= 4) ? i - 4 : 0;
        unsigned int c0 = 0, c1 = 0, c2 = 0;
        for (int ii = lo; ii <= i; ++ii) {
            c0 |= ro[ii * 3 + 0];
            c1 |= ro[ii * 3 + 1];
            c2 |= ro[ii * 3 + 2];
        }
        bmp[i * 3 + 0] = c0; bmp[i * 3 + 1] = c1; bmp[i * 3 + 2] = c2;
    }
    __syncthreads();
    const float* xp = x + plane * DB_PLANE;
    float* op = out + plane * DB_PLANE;
    for (int e = lane; e < DB_PLANE; e += 64) {
        int i = e / DB_W, j = e - i * DB_W;
        unsigned int wb = bmp[i * 3 + (j >> 5)] >> (j & 31);
        op[e] = (wb & 1u) ? 0.0f : xp[e] * scale;
    }
}

extern "C" void kernel_launch(void* const* d_in, const int* in_sizes, int n_in,
                              void* d_out, int out_size, void* d_ws, size_t ws_size,
                              hipStream_t stream) {
    const float* x = (const float*)d_in[0];
    const int* mask = (const int*)d_in[1];
    float* out = (float*)d_out;

    unsigned int* counts = (unsigned int*)d_ws;
    unsigned int* bits = (unsigned int*)((char*)d_ws + DB_CNT_BYTES);
    const size_t bits_bytes = (size_t)DB_NPLANES * DB_PLANE_WORDS * 4;
    const bool ws_has_bits = ws_size >= DB_CNT_BYTES + bits_bytes;

    int dev = 0, coop = 0;
    hipGetDevice(&dev);
    hipDeviceGetAttribute(&coop, hipDeviceAttributeCooperativeLaunch, dev);

    if (coop && ws_size >= DB_CNT_BYTES) {
        const int* a_mask = mask;
        const float4* a_x = (const float4*)x;
        unsigned int* a_counts = counts;
        float4* a_out = (float4*)out;
        void* args[] = {(void*)&a_mask, (void*)&a_x, (void*)&a_counts,
                        (void*)&a_out};
        hipError_t err = hipLaunchCooperativeKernel(
            (const void*)db_fused, dim3(DB_NBLK), dim3(256), args, 0, stream);
        if (err == hipSuccess) return;
    }

    if (ws_has_bits) {
        db_mask_kernel<<<DB_NPLANES / PPBLK, 256, 0, stream>>>(mask, bits,
                                                               counts);
        db_apply_bits<<<2048, 256, 0, stream>>>(
            (const float4*)x, bits, counts, (float4*)out);
    } else {
        db_count_kernel<<<DB_NPLANES / WPB, 256, 0, stream>>>(mask, counts);
        db_apply_recompute<<<DB_NPLANES / WPB, 256, 0, stream>>>(
            x, mask, counts, out);
    }
}

// Round 9
// 68.025 us; speedup vs baseline: 6.4901x; 6.4901x over previous
//
#include <hip/hip_runtime.h>

// DropBlock, N=64 C=64 H=80 W=80, block_size=5 (top/left-clipped window max).
// R9: bitplane bitboards. Mask kernel loads int4 (16B/lane, G13 sweet spot;
// R7's dword loads ran ~3.6 TB/s), 4 ballots/load yield 4 bitplanes directly
// (plane w bit l = elem 4l+w). Width-5 row OR in plane space = 13 u32 ops.
// Wave = plane -> zero barriers. Apply reads uint4 of planes per row (L1-hit).
// Lessons kept: no atomics (R3: ~20ns serialized each), no memset in graph
// (R4), NO cooperative grid.sync (R8: ~400us on ROCm/8-XCD).
#define DB_H 80
#define DB_W 80
#define DB_PLANE (DB_H * DB_W)               // 6400
#define DB_NPLANES 4096                      // N*C
#define DB_TOTAL (DB_PLANE * DB_NPLANES)     // 26214400
#define DB_COUNT_F 26214400.0f               // 25 * 2^20 — exact in f32
#define DB_CNT_BYTES (DB_NPLANES * 4)        // 16384
#define DB_BP_UINT4 (DB_NPLANES * DB_H)      // 327680 uint4 = 5.24 MB
#define WPB 4

// Kernel 1: per-plane (per-wave) bitplane window-OR + zero count + BP store.
__global__ __launch_bounds__(256) void db_mask_bp(
    const int4* __restrict__ mask4,
    uint4* __restrict__ bp,                  // [NPLANES*80] plane words c0..c3
    unsigned int* __restrict__ counts)
{
    __shared__ unsigned long long G[WPB][26 * 4];   // ballot groups (+pad g=25)
    __shared__ unsigned int RO[WPB][DB_H * 4];      // row-OR planes
    const int wid = threadIdx.x >> 6, lane = threadIdx.x & 63;
    const int plane = blockIdx.x * WPB + wid;
    const int4* mp = mask4 + plane * (DB_PLANE / 4);   // 1600 int4/plane
    unsigned long long* Gp = G[wid];
    unsigned int* ro = RO[wid];

    if (lane < 4) Gp[25 * 4 + lane] = 0ULL;   // zero pad group 25

    // Phase 1: 25 int4 wave-loads (1KB each) in bursts of 5; 4 ballots/load
    // give planes 0..3 of a 256-elem group (bit l = lane l's component w).
    #pragma unroll 1
    for (int c = 0; c < 5; ++c) {
        int4 v[5];
        #pragma unroll
        for (int k = 0; k < 5; ++k) v[k] = mp[(c * 5 + k) * 64 + lane];
        #pragma unroll
        for (int k = 0; k < 5; ++k) {
            unsigned long long b0 = __ballot(v[k].x & 1);
            unsigned long long b1 = __ballot(v[k].y & 1);
            unsigned long long b2 = __ballot(v[k].z & 1);
            unsigned long long b3 = __ballot(v[k].w & 1);
            if (lane < 4) {
                unsigned long long bw =
                    (lane == 0) ? b0 : (lane == 1) ? b1 : (lane == 2) ? b2 : b3;
                Gp[(c * 5 + k) * 4 + lane] = bw;
            }
        }
    }
    // Wave-local from here: program order + lgkmcnt, no __syncthreads needed.

    // Phase 2: row sliding-OR (width 5, left-clipped) in bitplane space.
    // Row r = 20 bits per plane, extracted at bit offset l0 of group g.
    #pragma unroll 1
    for (int rr = 0; rr < 2; ++rr) {
        const int r = rr * 64 + lane;
        if (r < DB_H) {
            const int e0 = r * DB_W;
            const int g = e0 >> 8;
            const int l0 = (e0 & 255) >> 2;          // 20r mod 64
            const unsigned long long* Gw = Gp + g * 4;
            const bool cross = l0 > 44;              // l0+20 > 64
            const int sh = 64 - l0;                  // only used when cross
            unsigned long long s;
            unsigned p0, p1, p2, p3;
            s = Gw[0] >> l0; if (cross) s |= Gw[4] << sh; p0 = (unsigned)s & 0xFFFFF;
            s = Gw[1] >> l0; if (cross) s |= Gw[5] << sh; p1 = (unsigned)s & 0xFFFFF;
            s = Gw[2] >> l0; if (cross) s |= Gw[6] << sh; p2 = (unsigned)s & 0xFFFFF;
            s = Gw[3] >> l0; if (cross) s |= Gw[7] << sh; p3 = (unsigned)s & 0xFFFFF;
            // OR of element-shifts s=0..4 (verified): plane rotation + carry.
            const unsigned q23 = p2 | p3, q123 = p1 | q23, t = p0 | q123;
            const unsigned a01 = p0 | p1, a012 = a01 | p2;
            const unsigned r0 = (p0   | (t    << 1)) & 0xFFFFF;
            const unsigned r1 = (a01  | (q123 << 1)) & 0xFFFFF;
            const unsigned r2 = (a012 | (q23  << 1)) & 0xFFFFF;
            const unsigned r3 = (t    | (p3   << 1)) & 0xFFFFF;
            ((uint4*)ro)[r] = make_uint4(r0, r1, r2, r3);
        }
    }

    // Phase 3: col OR over rows i-4..i (top clip), zeros count, store planes.
    unsigned int zeros = 0;
    #pragma unroll 1
    for (int rr = 0; rr < 2; ++rr) {
        const int i = rr * 64 + lane;
        if (i < DB_H) {
            const int lo = (i >= 4) ? i - 4 : 0;
            unsigned c0 = 0, c1 = 0, c2 = 0, c3 = 0;
            for (int ii = lo; ii <= i; ++ii) {
                const uint4 rv = ((const uint4*)ro)[ii];
                c0 |= rv.x; c1 |= rv.y; c2 |= rv.z; c3 |= rv.w;
            }
            zeros += 80u - __popc(c0) - __popc(c1) - __popc(c2) - __popc(c3);
            bp[plane * DB_H + i] = make_uint4(c0, c1, c2, c3);
        }
    }
    for (int off = 32; off > 0; off >>= 1)
        zeros += (unsigned int)__shfl_down((int)zeros, off, 64);
    if (lane == 0) counts[plane] = zeros;    // plain store, no init needed
}

// Kernel 2: out = blocked ? 0 : x * (countM / count_zeros), float4 stream.
// Prologue: block-local sum of 4096 per-plane counts (16KB, L3-resident).
__global__ __launch_bounds__(256) void db_apply_bp(
    const float4* __restrict__ x,
    const uint4* __restrict__ bp,
    const unsigned int* __restrict__ counts,
    float4* __restrict__ out)
{
    __shared__ float s_scale;
    __shared__ unsigned int s_part[4];
    {
        const uint4* cp = (const uint4*)counts;   // 1024 uint4
        unsigned int c = 0;
        #pragma unroll
        for (int k = 0; k < 4; ++k) {
            uint4 v = cp[k * 256 + threadIdx.x];
            c += v.x + v.y + v.z + v.w;
        }
        for (int off = 32; off > 0; off >>= 1)
            c += (unsigned int)__shfl_down((int)c, off, 64);
        if ((threadIdx.x & 63) == 0) s_part[threadIdx.x >> 6] = c;
        __syncthreads();
        if (threadIdx.x == 0)
            s_scale = DB_COUNT_F /
                      (float)(s_part[0] + s_part[1] + s_part[2] + s_part[3]);
        __syncthreads();
    }
    const float scale = s_scale;
    const unsigned NG = DB_TOTAL / 4;             // 6553600 float4s
    const unsigned stride = gridDim.x * blockDim.x;
    #pragma unroll 2
    for (unsigned g = blockIdx.x * blockDim.x + threadIdx.x; g < NG; g += stride) {
        const unsigned plane = g / 1600u;         // float4s per plane
        const unsigned gp = g - plane * 1600u;
        const unsigned i = gp / 20u;              // row (20 float4s per row)
        const unsigned l = gp - i * 20u;          // bit index in each plane
        const uint4 b = bp[plane * DB_H + i];     // L1-hit (same 16B x20 iters)
        const float4 v = x[g];
        float4 o;
        o.x = ((b.x >> l) & 1u) ? 0.0f : v.x * scale;
        o.y = ((b.y >> l) & 1u) ? 0.0f : v.y * scale;
        o.z = ((b.z >> l) & 1u) ? 0.0f : v.z * scale;
        o.w = ((b.w >> l) & 1u) ? 0.0f : v.w * scale;
        out[g] = o;
    }
}

// ---- Fallback (ws too small for bp): R7 recompute path, known-good. ----
__global__ __launch_bounds__(256) void db_count_kernel(
    const int* __restrict__ mask,
    unsigned int* __restrict__ counts)
{
    __shared__ unsigned long long P[WPB][104];
    __shared__ unsigned int RO[WPB][DB_H * 3];
    const int wid = threadIdx.x >> 6, lane = threadIdx.x & 63;
    const int plane = blockIdx.x * WPB + wid;
    const int* mp = mask + plane * DB_PLANE;
    unsigned long long* Pp = P[wid];
    unsigned int* ro = RO[wid];
    #pragma unroll 1
    for (int c = 0; c < 10; ++c) {
        int v[10];
        #pragma unroll
        for (int k = 0; k < 10; ++k) v[k] = mp[(c * 10 + k) * 64 + lane];
        #pragma unroll
        for (int k = 0; k < 10; ++k) {
            unsigned long long bal = __ballot(v[k] & 1);
            if (lane == 0) Pp[c * 10 + k] = bal;
        }
    }
    if (lane < 4) Pp[100 + lane] = 0ULL;
    __syncthreads();
    for (int r = lane; r < DB_H; r += 64) {
        const int bitpos = r * DB_W;
        const int q = bitpos >> 6, off = bitpos & 63;
        unsigned long long a, b;
        if (off) {
            a = (Pp[q] >> off) | (Pp[q + 1] << (64 - off));
            b = (Pp[q + 1] >> off) | (Pp[q + 2] << (64 - off));
        } else {
            a = Pp[q]; b = Pp[q + 1];
        }
        b &= 0xFFFFULL;
        unsigned long long ra = a, rb = b;
        #pragma unroll
        for (int s = 1; s <= 4; ++s) {
            ra |= a << s;
            rb |= (b << s) | (a >> (64 - s));
        }
        rb &= 0xFFFFULL;
        ro[r * 3 + 0] = (unsigned int)ra;
        ro[r * 3 + 1] = (unsigned int)(ra >> 32);
        ro[r * 3 + 2] = (unsigned int)rb;
    }
    __syncthreads();
    unsigned int zeros = 0;
    for (int i = lane; i < DB_H; i += 64) {
        const int lo = (i >= 4) ? i - 4 : 0;
        unsigned int c0 = 0, c1 = 0, c2 = 0;
        for (int ii = lo; ii <= i; ++ii) {
            c0 |= ro[ii * 3 + 0];
            c1 |= ro[ii * 3 + 1];
            c2 |= ro[ii * 3 + 2];
        }
        zeros += 80u - __popc(c0) - __popc(c1) - __popc(c2);
    }
    for (int off = 32; off > 0; off >>= 1)
        zeros += (unsigned int)__shfl_down((int)zeros, off, 64);
    if (lane == 0) counts[plane] = zeros;
}

__global__ __launch_bounds__(256) void db_apply_recompute(
    const float* __restrict__ x,
    const int* __restrict__ mask,
    const unsigned int* __restrict__ counts,
    float* __restrict__ out)
{
    __shared__ unsigned long long P[WPB][104];
    __shared__ unsigned int RO[WPB][DB_H * 3];
    __shared__ unsigned int BM[WPB][DB_H * 3];
    __shared__ float s_scale;
    __shared__ unsigned int s_part[4];
    {
        const uint4* cp = (const uint4*)counts;
        unsigned int c = 0;
        #pragma unroll
        for (int k = 0; k < 4; ++k) {
            uint4 v = cp[k * 256 + threadIdx.x];
            c += v.x + v.y + v.z + v.w;
        }
        for (int off = 32; off > 0; off >>= 1)
            c += (unsigned int)__shfl_down((int)c, off, 64);
        if ((threadIdx.x & 63) == 0) s_part[threadIdx.x >> 6] = c;
        __syncthreads();
        if (threadIdx.x == 0)
            s_scale = DB_COUNT_F /
                      (float)(s_part[0] + s_part[1] + s_part[2] + s_part[3]);
        __syncthreads();
    }
    const float scale = s_scale;
    const int wid = threadIdx.x >> 6, lane = threadIdx.x & 63;
    const int plane = blockIdx.x * WPB + wid;
    const int* mp = mask + plane * DB_PLANE;
    unsigned long long* Pp = P[wid];
    unsigned int* ro = RO[wid];
    #pragma unroll 1
    for (int c = 0; c < 10; ++c) {
        int v[10];
        #pragma unroll
        for (int k = 0; k < 10; ++k) v[k] = mp[(c * 10 + k) * 64 + lane];
        #pragma unroll
        for (int k = 0; k < 10; ++k) {
            unsigned long long bal = __ballot(v[k] & 1);
            if (lane == 0) Pp[c * 10 + k] = bal;
        }
    }
    if (lane < 4) Pp[100 + lane] = 0ULL;
    __syncthreads();
    for (int r = lane; r < DB_H; r += 64) {
        const int bitpos = r * DB_W;
        const int q = bitpos >> 6, off = bitpos & 63;
        unsigned long long a, b;
        if (off) {
            a = (Pp[q] >> off) | (Pp[q + 1] << (64 - off));
            b = (Pp[q + 1] >> off) | (Pp[q + 2] << (64 - off));
        } else {
            a = Pp[q]; b = Pp[q + 1];
        }
        b &= 0xFFFFULL;
        unsigned long long ra = a, rb = b;
        #pragma unroll
        for (int s = 1; s <= 4; ++s) {
            ra |= a << s;
            rb |= (b << s) | (a >> (64 - s));
        }
        rb &= 0xFFFFULL;
        ro[r * 3 + 0] = (unsigned int)ra;
        ro[r * 3 + 1] = (unsigned int)(ra >> 32);
        ro[r * 3 + 2] = (unsigned int)rb;
    }
    __syncthreads();
    unsigned int* bmp = BM[wid];
    for (int i = lane; i < DB_H; i += 64) {
        const int lo = (i >= 4) ? i - 4 : 0;
        unsigned int c0 = 0, c1 = 0, c2 = 0;
        for (int ii = lo; ii <= i; ++ii) {
            c0 |= ro[ii * 3 + 0];
            c1 |= ro[ii * 3 + 1];
            c2 |= ro[ii * 3 + 2];
        }
        bmp[i * 3 + 0] = c0; bmp[i * 3 + 1] = c1; bmp[i * 3 + 2] = c2;
    }
    __syncthreads();
    const float* xp = x + plane * DB_PLANE;
    float* op = out + plane * DB_PLANE;
    for (int e = lane; e < DB_PLANE; e += 64) {
        int i = e / DB_W, j = e - i * DB_W;
        unsigned int wb = bmp[i * 3 + (j >> 5)] >> (j & 31);
        op[e] = (wb & 1u) ? 0.0f : xp[e] * scale;
    }
}

extern "C" void kernel_launch(void* const* d_in, const int* in_sizes, int n_in,
                              void* d_out, int out_size, void* d_ws, size_t ws_size,
                              hipStream_t stream) {
    const float* x = (const float*)d_in[0];
    const int* mask = (const int*)d_in[1];
    float* out = (float*)d_out;

    unsigned int* counts = (unsigned int*)d_ws;
    uint4* bp = (uint4*)((char*)d_ws + DB_CNT_BYTES);
    const size_t need = DB_CNT_BYTES + (size_t)DB_BP_UINT4 * sizeof(uint4);

    if (ws_size >= need) {
        db_mask_bp<<<DB_NPLANES / WPB, 256, 0, stream>>>(
            (const int4*)mask, bp, counts);
        db_apply_bp<<<2048, 256, 0, stream>>>(
            (const float4*)x, bp, counts, (float4*)out);
    } else {
        db_count_kernel<<<DB_NPLANES / WPB, 256, 0, stream>>>(mask, counts);
        db_apply_recompute<<<DB_NPLANES / WPB, 256, 0, stream>>>(
            x, mask, counts, out);
    }
}